// Round 14
// baseline (224.017 us; speedup 1.0000x reference)
//
#include <hip/hip_runtime.h>
#include <hip/hip_fp16.h>

#define N_NODES 50000
#define N_EDGES 800000
#define DIM 128
#define FEAT_ELEMS (N_NODES * DIM)  // 6,400,000
#define STRIDE 64   // padded-CSR slots per node; max degree ~45 (Poisson lambda=16)
#define NB 391      // buckets of 128 nodes (dst >> 7)
#define BCAP 3072   // slots per bucket region; expected 2046, 22-sigma margin

typedef __attribute__((ext_vector_type(8))) _Float16 f16x8;
typedef __attribute__((ext_vector_type(4))) float f32x4;
typedef __attribute__((ext_vector_type(2))) float f32x2;

#define MFMA_F16 __builtin_amdgcn_mfma_f32_16x16x32_f16

// ---------------- Merged prep + bucket (one dispatch; gcnt zeroed by memset) ----
// blocks 0..111: prep_w -> single fp16 frag plane per W
// blocks 112..1135: x -> fp16 mirror + SPLIT fp8 mirrors (Qlo|Qhi, 3.2 MB each)
// blocks 1136..1526: bucket partition of edges (391 blocks)
// block 1527: zero the 6 fp8 dummy pad rows (index N_NODES)
// Slot (ks*8+ct): lane l holds W[k=32*ks+(l>>4)*8+j][n=16*ct+(l&15)], j=0..7.

__global__ __launch_bounds__(256) void prep_bucket_kernel(
    const float* __restrict__ w0, const float* __restrict__ w1,
    const float* __restrict__ w2, const float* __restrict__ w3,
    const float* __restrict__ w4, const float* __restrict__ w5,
    const float* __restrict__ w6, __half* __restrict__ dst,
    const float* __restrict__ x, __half* __restrict__ hm,
    unsigned char* __restrict__ qxlo, unsigned char* __restrict__ qxhi,
    unsigned char* __restrict__ q1lo, unsigned char* __restrict__ q1hi,
    unsigned char* __restrict__ q0lo, unsigned char* __restrict__ q0hi,
    const int* __restrict__ ei, int* __restrict__ gcnt,
    long long* __restrict__ ebuf) {
    __shared__ int hist[NB];
    __shared__ int base[NB];
    __shared__ int sh_is64;
    const int b = blockIdx.x;
    const int tid = threadIdx.x;
    if (b < 112) {
        const int wsel = b >> 4;   // 0..6
        const int chunk = b & 15;  // 0..15
        const float* W;
        switch (wsel) {
            case 0: W = w0; break;
            case 1: W = w1; break;
            case 2: W = w2; break;
            case 3: W = w3; break;
            case 4: W = w4; break;
            case 5: W = w5; break;
            default: W = w6; break;
        }
        __half* d = dst + (size_t)wsel * 16384;
        int idx = chunk * 1024 + tid;
#pragma unroll
        for (int t = 0; t < 4; ++t, idx += 256) {
            int k = idx >> 7, n = idx & 127;
            int ks = k >> 5, q = (k >> 3) & 3, j = k & 7;
            int ct = n >> 4, c = n & 15;
            int lane = q * 16 + c;
            int bas = ((ks * 8 + ct) * 64 + lane) * 8 + j;
            d[bas] = __float2half(W[idx]);
        }
    } else if (b < 1136) {
        int i = (b - 112) * 256 + tid;
        const int stride = 1024 * 256;
        const int n4 = FEAT_ELEMS / 4;
        for (; i < n4; i += stride) {
            float4 v = ((const float4*)x)[i];
            __half2 h0 = __floats2half2_rn(v.x, v.y);
            __half2 h1 = __floats2half2_rn(v.z, v.w);
            uint2 u;
            u.x = *(unsigned*)&h0;
            u.y = *(unsigned*)&h1;
            ((uint2*)hm)[i] = u;
            int p = __builtin_amdgcn_cvt_pk_fp8_f32(v.x, v.y, 0, false);
            p = __builtin_amdgcn_cvt_pk_fp8_f32(v.z, v.w, p, true);
            const int node = i >> 5;
            const int within = (i & 31) * 4;  // fp8-byte offset in 128-wide row
            if (within < 64)
                *(int*)(qxlo + (size_t)node * 64 + within) = p;
            else
                *(int*)(qxhi + (size_t)node * 64 + (within - 64)) = p;
        }
    } else if (b < 1527) {
        // ---- bucket partition (r13-proven structure) ----
        for (int i = tid; i < NB; i += 256) hist[i] = 0;
        if (tid == 0) {
            int o = 0;
            for (int i = 1; i < 64; i += 2) o |= ei[i];
            sh_is64 = (o == 0) ? 1 : 0;
        }
        __syncthreads();
        const int e0 = (b - 1136) * 2048;
        const int is64 = sh_is64;
        int sv[8], dv[8];
        int nl = 0;
#pragma unroll
        for (int k = 0; k < 8; ++k) {
            int e = e0 + k * 256 + tid;
            if (e < N_EDGES) {
                int s = is64 ? ei[2 * e] : ei[e];
                int d = is64 ? ei[2 * (N_EDGES + e)] : ei[N_EDGES + e];
                sv[nl] = s;
                dv[nl] = d;
                atomicAdd(&hist[d >> 7], 1);
                ++nl;
            }
        }
        __syncthreads();
        for (int i = tid; i < NB; i += 256) {
            int h = hist[i];
            base[i] = h ? atomicAdd(&gcnt[i], h) : 0;
        }
        __syncthreads();
        for (int i = tid; i < NB; i += 256) hist[i] = 0;  // reuse as cursor
        __syncthreads();
        for (int k = 0; k < nl; ++k) {
            int bb = dv[k] >> 7;
            int r = base[bb] + atomicAdd(&hist[bb], 1);
            if (r < BCAP)
                ebuf[(size_t)bb * BCAP + r] = ((long long)sv[k] << 32) | (unsigned)dv[k];
        }
    } else {
        // zero the 64 B dummy row (index N_NODES) of all 6 split mirrors
        if (tid < 16) *(unsigned*)(qxlo + (size_t)N_NODES * 64 + tid * 4) = 0;
        else if (tid < 32) *(unsigned*)(qxhi + (size_t)N_NODES * 64 + (tid - 16) * 4) = 0;
        else if (tid < 48) *(unsigned*)(q1lo + (size_t)N_NODES * 64 + (tid - 32) * 4) = 0;
        else if (tid < 64) *(unsigned*)(q1hi + (size_t)N_NODES * 64 + (tid - 48) * 4) = 0;
        else if (tid < 80) *(unsigned*)(q0lo + (size_t)N_NODES * 64 + (tid - 64) * 4) = 0;
        else if (tid < 96) *(unsigned*)(q0hi + (size_t)N_NODES * 64 + (tid - 80) * 4) = 0;
    }
}

// ---------------- Phase B: per-bucket padded-CSR build (LDS atomics only) -------
// List padding to x8 folded into the per-node epilogue (dummy idx N_NODES ->
// zero fp8 rows), eliminating all gather tail iterations.

__global__ __launch_bounds__(256) void build_kernel(const int* __restrict__ gcnt,
                                                    const long long* __restrict__ ebuf,
                                                    int* __restrict__ cnt,
                                                    int* __restrict__ col_idx) {
    __shared__ int cur[128];
    const int b = blockIdx.x;
    const int tid = threadIdx.x;
    if (tid < 128) cur[tid] = 0;
    __syncthreads();
    int n = gcnt[b];
    if (n > BCAP) n = BCAP;
    const long long* eb = ebuf + (size_t)b * BCAP;
    for (int i = tid; i < n; i += 256) {
        long long p = eb[i];
        int d = (int)(p & 0xFFFFFFFFll);
        int s = (int)(p >> 32);
        int slot = atomicAdd(&cur[d & 127], 1);
        if (slot < STRIDE) col_idx[d * STRIDE + slot] = s;
    }
    __syncthreads();
    int node = b * 128 + tid;
    if (tid < 128 && node < N_NODES) {
        int c = cur[tid];
        if (c > STRIDE) c = STRIDE;
        const int p = (c + 7) & ~7;  // pad to multiple of 8
        for (int s = c; s < p; ++s) col_idx[node * STRIDE + s] = N_NODES;
        cnt[node] = p;
    }
}

// ---------------- Fused GIN layer: 2-wave block per 16-row tile ----------------
// r14: SPLIT-MIRROR gather. r9 PMC: Q-gather HBM fetch ~7 MB (near-ideal) but
// gin_layer latency-dominated -> bottleneck is per-XCD L2 MISS SERVICE: 6.4 MB
// random working set thrashes the 4 MB XCD L2. Fix: fp8 mirror split into
// Qlo[N][64] + Qhi[N][64] (3.2 MB each); gather runs 2 temporally-separated
// passes (all 16 rows x lo, then x hi) so each pass's random set FITS L2.
// Per-element summation order identical to r13 (bit-identical numerics).
// Thread map: 8 lanes/half-row (uint2 loads, proven no-spill width), 16 rows
// per pass in one shot; indices via 2x int4 (direct .xyzw).
// MFMA passes unchanged (column-half split, 3 barriers, 8 KB LDS).
// LAST=false: epi-2b coalesced read-back + residual -> fp16 state + split fp8.
// LAST=true: pass 3 = h3 @ Wh + bh -> fp32 out (head fused).

template <bool LAST>
__global__ __launch_bounds__(128, 4) void gin_layer_kernel(
    const __half* __restrict__ Hs,          // fp16 state (self + residual source)
    const unsigned char* __restrict__ Qlo,  // fp8 mirror lo half (+ zero row)
    const unsigned char* __restrict__ Qhi,  // fp8 mirror hi half (+ zero row)
    const int* __restrict__ cnt,
    const int* __restrict__ col_idx,
    const __half* __restrict__ W1f,
    const __half* __restrict__ W2f,
    const __half* __restrict__ Whf,         // head W frags (LAST only)
    const float* __restrict__ b1,
    const float* __restrict__ b2,
    const float* __restrict__ bh,           // head bias (LAST only)
    __half* __restrict__ Hout,
    unsigned char* __restrict__ Qoutlo,
    unsigned char* __restrict__ Qouthi,
    float* __restrict__ Cout) {
    __shared__ __align__(16) __half tl[2048];  // 16x128 t tile; reused for h'
    __shared__ __align__(16) __half ul[2048];  // 16x128 u tile
    const int tid = threadIdx.x;
    const int lane = tid & 63;
    const int wid = tid >> 6;   // 0..1: column-half owner
    const int c = lane & 15;
    const int q = lane >> 4;
    const int R = blockIdx.x * 16;  // tile rows (50000 = 3125*16, grid exact)

    // ---- Phase G: gather t = h[v] + sum_fp8 h[src] -> tl, two L2-sized passes --
    {
        const int row = tid >> 3;        // local row 0..15 (one per thread-group)
        const int d0b = (tid & 7) * 8;   // byte offset within 64B half-row
        const size_t grow = (size_t)(R + row);
        const int d = cnt[grow];         // padded multiple of 8, <= 64
        const int* ci = col_idx + grow * STRIDE;
        const int swz = (row & 7) << 3;
#define ACCQ(U)                                                             \
    {                                                                       \
        f32x2 g0 = __builtin_amdgcn_cvt_pk_f32_fp8((int)(U).x, false);      \
        f32x2 g1 = __builtin_amdgcn_cvt_pk_f32_fp8((int)(U).x, true);       \
        f32x2 g2 = __builtin_amdgcn_cvt_pk_f32_fp8((int)(U).y, false);      \
        f32x2 g3 = __builtin_amdgcn_cvt_pk_f32_fp8((int)(U).y, true);       \
        acc[0] += g0.x; acc[1] += g0.y; acc[2] += g1.x; acc[3] += g1.y;     \
        acc[4] += g2.x; acc[5] += g2.y; acc[6] += g3.x; acc[7] += g3.y;     \
    }
#define GATHER_PASS(QP, CB)                                                     \
    {                                                                           \
        float acc[8];                                                           \
        {                                                                       \
            uint4 sv = *(const uint4*)(Hs + grow * DIM + (CB) + d0b);           \
            const __half2* sp = (const __half2*)&sv;                            \
            float2 s0 = __half22float2(sp[0]), s1 = __half22float2(sp[1]);      \
            float2 s2 = __half22float2(sp[2]), s3 = __half22float2(sp[3]);      \
            acc[0] = s0.x; acc[1] = s0.y; acc[2] = s1.x; acc[3] = s1.y;         \
            acc[4] = s2.x; acc[5] = s2.y; acc[6] = s3.x; acc[7] = s3.y;         \
        }                                                                       \
        for (int j = 0; j < d; j += 8) {                                        \
            int4 ia = *(const int4*)(ci + j);                                   \
            int4 ib = *(const int4*)(ci + j + 4);                               \
            uint2 u0 = *(const uint2*)((QP) + (size_t)ia.x * 64 + d0b);         \
            uint2 u1 = *(const uint2*)((QP) + (size_t)ia.y * 64 + d0b);         \
            uint2 u2 = *(const uint2*)((QP) + (size_t)ia.z * 64 + d0b);         \
            uint2 u3 = *(const uint2*)((QP) + (size_t)ia.w * 64 + d0b);         \
            uint2 u4 = *(const uint2*)((QP) + (size_t)ib.x * 64 + d0b);         \
            uint2 u5 = *(const uint2*)((QP) + (size_t)ib.y * 64 + d0b);         \
            uint2 u6 = *(const uint2*)((QP) + (size_t)ib.z * 64 + d0b);         \
            uint2 u7 = *(const uint2*)((QP) + (size_t)ib.w * 64 + d0b);         \
            ACCQ(u0) ACCQ(u1) ACCQ(u2) ACCQ(u3)                                 \
            ACCQ(u4) ACCQ(u5) ACCQ(u6) ACCQ(u7)                                 \
        }                                                                       \
        uint4 o;                                                                \
        __half2* op = (__half2*)&o;                                             \
        op[0] = __floats2half2_rn(acc[0], acc[1]);                              \
        op[1] = __floats2half2_rn(acc[2], acc[3]);                              \
        op[2] = __floats2half2_rn(acc[4], acc[5]);                              \
        op[3] = __floats2half2_rn(acc[6], acc[7]);                              \
        *(uint4*)&tl[row * 128 + (((CB) + d0b) ^ swz)] = o;                     \
    }
        GATHER_PASS(Qlo, 0)     // pass A: lo halves (3.2 MB set, fits XCD L2)
        GATHER_PASS(Qhi, 64)    // pass B: hi halves
#undef GATHER_PASS
#undef ACCQ
    }
    __syncthreads();  // B1: t tile complete

    // ---- A frags from tl (rows 0..15 = both waves' gather output) ----
    f16x8 a[4];
#pragma unroll
    for (int ks = 0; ks < 4; ++ks)
        a[ks] = *(const f16x8*)&tl[c * 128 + ((ks * 32 + q * 8) ^ ((c & 7) << 3))];

    // ---- pass 1: u(16x64 per wave) = t @ W1 (B frags streamed from L2) ----
    f32x4 acc1[4];
#pragma unroll
    for (int t = 0; t < 4; ++t) acc1[t] = (f32x4){0.f, 0.f, 0.f, 0.f};
#pragma unroll
    for (int ks = 0; ks < 4; ++ks) {
#pragma unroll
        for (int t = 0; t < 4; ++t) {
            const int ctg = wid * 4 + t;
            f16x8 b = *(const f16x8*)(W1f + (ks * 8 + ctg) * 512 + lane * 8);
            acc1[t] = MFMA_F16(a[ks], b, acc1[t], 0, 0, 0);
        }
    }

    // ---- epilogue 1: relu(u + b1) -> ul (row&7 swizzle) ----
#pragma unroll
    for (int t = 0; t < 4; ++t) {
        const int col = (wid * 4 + t) * 16 + c;
        const float bv = b1[col];
#pragma unroll
        for (int rr = 0; rr < 4; ++rr) {
            const int rl = q * 4 + rr;
            ul[rl * 128 + (col ^ ((rl & 7) << 3))] =
                __float2half(fmaxf(acc1[t][rr] + bv, 0.f));
        }
    }
    __syncthreads();  // B2: u tile complete (also: all t reads done)

    // ---- pass 2: h' = u @ W2 (full u rows; own column half) ----
    f32x4 acc2[4];
#pragma unroll
    for (int t = 0; t < 4; ++t) acc2[t] = (f32x4){0.f, 0.f, 0.f, 0.f};
#pragma unroll
    for (int ks = 0; ks < 4; ++ks) {
        f16x8 ua = *(const f16x8*)&ul[c * 128 + ((ks * 32 + q * 8) ^ ((c & 7) << 3))];
#pragma unroll
        for (int t = 0; t < 4; ++t) {
            const int ctg = wid * 4 + t;
            f16x8 b = *(const f16x8*)(W2f + (ks * 8 + ctg) * 512 + lane * 8);
            acc2[t] = MFMA_F16(ua, b, acc2[t], 0, 0, 0);
        }
    }

    // ---- epilogue 2a: +b2 -> tl (t dead; q<<4 swizzle: addr = f(row,col)) ----
#pragma unroll
    for (int t = 0; t < 4; ++t) {
        const int col = (wid * 4 + t) * 16 + c;
        const float bv = b2[col];
#pragma unroll
        for (int rr = 0; rr < 4; ++rr) {
            const int rl = q * 4 + rr;
            tl[rl * 128 + (col ^ (q << 4))] = __float2half(acc2[t][rr] + bv);
        }
    }
    __syncthreads();  // B3: h' tile complete

    if (!LAST) {
        // ---- epi 2b: coalesced read-back + residual -> fp16 state + split fp8 --
        // 128 thr: 8 thr/row, 16 halfs each (chunks c0 and c0+64)
        const int row2 = tid >> 3;       // 0..15
        const int cb = (tid & 7) * 8;
        const size_t grow = (size_t)(R + row2);
#pragma unroll
        for (int k = 0; k < 2; ++k) {
            const int c0 = cb + k * 64;
            uint4 hv = *(uint4*)&tl[row2 * 128 + (c0 ^ ((row2 >> 2) << 4))];
            const __half2* hp = (const __half2*)&hv;
            float2 t0 = __half22float2(hp[0]), t1 = __half22float2(hp[1]);
            float2 t2 = __half22float2(hp[2]), t3 = __half22float2(hp[3]);
            float f0 = t0.x, f1 = t0.y, f2 = t1.x, f3 = t1.y;
            float f4 = t2.x, f5 = t2.y, f6 = t3.x, f7 = t3.y;
            {
                uint4 rv = *(const uint4*)(Hs + grow * DIM + c0);
                const __half2* rp = (const __half2*)&rv;
                float2 r0 = __half22float2(rp[0]), r1 = __half22float2(rp[1]);
                float2 r2 = __half22float2(rp[2]), r3 = __half22float2(rp[3]);
                f0 += r0.x; f1 += r0.y; f2 += r1.x; f3 += r1.y;
                f4 += r2.x; f5 += r2.y; f6 += r3.x; f7 += r3.y;
            }
            uint4 ov;
            __half2* op = (__half2*)&ov;
            op[0] = __floats2half2_rn(f0, f1);
            op[1] = __floats2half2_rn(f2, f3);
            op[2] = __floats2half2_rn(f4, f5);
            op[3] = __floats2half2_rn(f6, f7);
            *(uint4*)(Hout + grow * DIM + c0) = ov;
            int q0 = __builtin_amdgcn_cvt_pk_fp8_f32(f0, f1, 0, false);
            q0 = __builtin_amdgcn_cvt_pk_fp8_f32(f2, f3, q0, true);
            int q1 = __builtin_amdgcn_cvt_pk_fp8_f32(f4, f5, 0, false);
            q1 = __builtin_amdgcn_cvt_pk_fp8_f32(f6, f7, q1, true);
            uint2 qv;
            qv.x = (unsigned)q0;
            qv.y = (unsigned)q1;
            if (k == 0)
                *(uint2*)(Qoutlo + grow * 64 + cb) = qv;
            else
                *(uint2*)(Qouthi + grow * 64 + cb) = qv;
        }
    } else {
        // ---- pass 3 (head): out = h3 @ Wh + bh -> fp32 (own column half) ----
        f32x4 acc3[4];
#pragma unroll
        for (int t = 0; t < 4; ++t) acc3[t] = (f32x4){0.f, 0.f, 0.f, 0.f};
#pragma unroll
        for (int ks = 0; ks < 4; ++ks) {
            f16x8 ha =
                *(const f16x8*)&tl[c * 128 + ((ks * 32 + q * 8) ^ ((c >> 2) << 4))];
#pragma unroll
            for (int t = 0; t < 4; ++t) {
                const int ctg = wid * 4 + t;
                f16x8 b = *(const f16x8*)(Whf + (ks * 8 + ctg) * 512 + lane * 8);
                acc3[t] = MFMA_F16(ha, b, acc3[t], 0, 0, 0);
            }
        }
#pragma unroll
        for (int t = 0; t < 4; ++t) {
            const int col = (wid * 4 + t) * 16 + c;
            const float bv = bh[col];
#pragma unroll
            for (int rr = 0; rr < 4; ++rr) {
                const int row = R + q * 4 + rr;
                Cout[(size_t)row * DIM + col] = acc3[t][rr] + bv;
            }
        }
    }
}

// ---------------- Launch ----------------

extern "C" void kernel_launch(void* const* d_in, const int* in_sizes, int n_in,
                              void* d_out, int out_size, void* d_ws, size_t ws_size,
                              hipStream_t stream) {
    const float* x = (const float*)d_in[0];
    const int* ei = (const int*)d_in[1];
    const float* w1[3] = {(const float*)d_in[2], (const float*)d_in[6], (const float*)d_in[10]};
    const float* b1[3] = {(const float*)d_in[3], (const float*)d_in[7], (const float*)d_in[11]};
    const float* w2[3] = {(const float*)d_in[4], (const float*)d_in[8], (const float*)d_in[12]};
    const float* b2[3] = {(const float*)d_in[5], (const float*)d_in[9], (const float*)d_in[13]};
    const float* wh = (const float*)d_in[14];
    const float* bh = (const float*)d_in[15];
    float* out = (float*)d_out;

    char* ws = (char*)d_ws;
    const size_t HFEAT = (size_t)FEAT_ELEMS * sizeof(__half);  // 12.8 MB
    const size_t QH = (size_t)N_NODES * 64 + 64;               // 3.2 MB + pad row
    size_t off = 0;
    int* cnt = (int*)(ws + off);                         off += 200704;
    int* col_idx = (int*)(ws + off);                     off += (size_t)N_NODES * STRIDE * 4;
    int* gcnt = (int*)(ws + off);                        off += 4096;
    __half* Wf = (__half*)(ws + off);                    off += 7 * 32768;
    long long* ebuf = (long long*)(ws + off);            off += (size_t)NB * BCAP * 8;
    __half* HMx = (__half*)(ws + off);                   off += HFEAT;  // x fp16
    __half* HM1 = (__half*)(ws + off);                   off += HFEAT;  // h1 fp16
    __half* HM0 = (__half*)(ws + off);                   off += HFEAT;  // h2 fp16
    unsigned char* Qxlo = (unsigned char*)(ws + off);    off += QH;
    unsigned char* Qxhi = (unsigned char*)(ws + off);    off += QH;
    unsigned char* Q1lo = (unsigned char*)(ws + off);    off += QH;
    unsigned char* Q1hi = (unsigned char*)(ws + off);    off += QH;
    unsigned char* Q0lo = (unsigned char*)(ws + off);    off += QH;
    unsigned char* Q0hi = (unsigned char*)(ws + off);    off += QH;

    const int GIN_BLKS = N_NODES / 16;  // 3125 (2 waves per 16-row tile)

    // ---- prep+bucket (merged) + padded-CSR build ----
    (void)hipMemsetAsync(gcnt, 0, NB * sizeof(int), stream);
    prep_bucket_kernel<<<1528, 256, 0, stream>>>(
        w1[0], w2[0], w1[1], w2[1], w1[2], w2[2], wh, Wf, x, HMx,
        Qxlo, Qxhi, Q1lo, Q1hi, Q0lo, Q0hi, ei, gcnt, ebuf);
    build_kernel<<<NB, 256, 0, stream>>>(gcnt, ebuf, cnt, col_idx);

#define WF(i) (Wf + (size_t)(i) * 16384)

    // Layer 0: gather(HMx, Qx) + MLP (res=HMx) -> HM1 + Q1
    gin_layer_kernel<false><<<GIN_BLKS, 128, 0, stream>>>(
        HMx, Qxlo, Qxhi, cnt, col_idx, WF(0), WF(1), nullptr, b1[0], b2[0], nullptr,
        HM1, Q1lo, Q1hi, nullptr);

    // Layer 1: gather(HM1, Q1) + MLP (res=HM1) -> HM0 + Q0
    gin_layer_kernel<false><<<GIN_BLKS, 128, 0, stream>>>(
        HM1, Q1lo, Q1hi, cnt, col_idx, WF(2), WF(3), nullptr, b1[1], b2[1], nullptr,
        HM0, Q0lo, Q0hi, nullptr);

    // Layer 2 + head: gather(HM0, Q0) + MLP (no res) + h3@wh+bh -> out fp32
    gin_layer_kernel<true><<<GIN_BLKS, 128, 0, stream>>>(
        HM0, Q0lo, Q0hi, cnt, col_idx, WF(4), WF(5), WF(6), b1[2], b2[2], bh,
        nullptr, nullptr, nullptr, out);
#undef WF
}

// Round 15
// 213.638 us; speedup vs baseline: 1.0486x; 1.0486x over previous
//
#include <hip/hip_runtime.h>
#include <hip/hip_fp16.h>

#define N_NODES 50000
#define N_EDGES 800000
#define DIM 128
#define FEAT_ELEMS (N_NODES * DIM)  // 6,400,000
#define STRIDE 64   // padded-CSR slots per node; max degree ~45 (Poisson lambda=16)
#define NB 391      // buckets of 128 nodes (dst >> 7)
#define BCAP 3072   // slots per bucket region; expected 2046, 22-sigma margin

typedef __attribute__((ext_vector_type(8))) _Float16 f16x8;
typedef __attribute__((ext_vector_type(4))) float f32x4;
typedef __attribute__((ext_vector_type(2))) float f32x2;

#define MFMA_F16 __builtin_amdgcn_mfma_f32_16x16x32_f16

// ---------------- Merged prep + bucket (one dispatch; gcnt zeroed by memset) ----
// r15: r13's proven pieces + r14's (independent) prep/bucket merge. The r14
// split-mirror gather is REVERTED (falsified: 2x index reads + 2x serial
// windows cost more than L2 hit-rate bought).
// blocks 0..111: prep_w -> single fp16 frag plane per W
// blocks 112..1135: x -> fp16 mirror + fp8 e4m3 mirror (single, row=128B line)
// blocks 1136..1526: bucket partition of edges (391 blocks)
// block 1527: zero the 3 fp8 dummy pad rows (index N_NODES)
// Slot (ks*8+ct): lane l holds W[k=32*ks+(l>>4)*8+j][n=16*ct+(l&15)], j=0..7.

__global__ __launch_bounds__(256) void prep_bucket_kernel(
    const float* __restrict__ w0, const float* __restrict__ w1,
    const float* __restrict__ w2, const float* __restrict__ w3,
    const float* __restrict__ w4, const float* __restrict__ w5,
    const float* __restrict__ w6, __half* __restrict__ dst,
    const float* __restrict__ x, __half* __restrict__ hm,
    unsigned char* __restrict__ qx, unsigned char* __restrict__ q1,
    unsigned char* __restrict__ q0, const int* __restrict__ ei,
    int* __restrict__ gcnt, long long* __restrict__ ebuf) {
    __shared__ int hist[NB];
    __shared__ int base[NB];
    __shared__ int sh_is64;
    const int b = blockIdx.x;
    const int tid = threadIdx.x;
    if (b < 112) {
        const int wsel = b >> 4;   // 0..6
        const int chunk = b & 15;  // 0..15
        const float* W;
        switch (wsel) {
            case 0: W = w0; break;
            case 1: W = w1; break;
            case 2: W = w2; break;
            case 3: W = w3; break;
            case 4: W = w4; break;
            case 5: W = w5; break;
            default: W = w6; break;
        }
        __half* d = dst + (size_t)wsel * 16384;
        int idx = chunk * 1024 + tid;
#pragma unroll
        for (int t = 0; t < 4; ++t, idx += 256) {
            int k = idx >> 7, n = idx & 127;
            int ks = k >> 5, q = (k >> 3) & 3, j = k & 7;
            int ct = n >> 4, c = n & 15;
            int lane = q * 16 + c;
            int bas = ((ks * 8 + ct) * 64 + lane) * 8 + j;
            d[bas] = __float2half(W[idx]);
        }
    } else if (b < 1136) {
        int i = (b - 112) * 256 + tid;
        const int stride = 1024 * 256;
        const int n4 = FEAT_ELEMS / 4;
        for (; i < n4; i += stride) {
            float4 v = ((const float4*)x)[i];
            __half2 h0 = __floats2half2_rn(v.x, v.y);
            __half2 h1 = __floats2half2_rn(v.z, v.w);
            uint2 u;
            u.x = *(unsigned*)&h0;
            u.y = *(unsigned*)&h1;
            ((uint2*)hm)[i] = u;
            int p = __builtin_amdgcn_cvt_pk_fp8_f32(v.x, v.y, 0, false);
            p = __builtin_amdgcn_cvt_pk_fp8_f32(v.z, v.w, p, true);
            ((int*)qx)[i] = p;
        }
    } else if (b < 1527) {
        // ---- bucket partition (proven structure) ----
        for (int i = tid; i < NB; i += 256) hist[i] = 0;
        if (tid == 0) {
            int o = 0;
            for (int i = 1; i < 64; i += 2) o |= ei[i];
            sh_is64 = (o == 0) ? 1 : 0;
        }
        __syncthreads();
        const int e0 = (b - 1136) * 2048;
        const int is64 = sh_is64;
        int sv[8], dv[8];
        int nl = 0;
#pragma unroll
        for (int k = 0; k < 8; ++k) {
            int e = e0 + k * 256 + tid;
            if (e < N_EDGES) {
                int s = is64 ? ei[2 * e] : ei[e];
                int d = is64 ? ei[2 * (N_EDGES + e)] : ei[N_EDGES + e];
                sv[nl] = s;
                dv[nl] = d;
                atomicAdd(&hist[d >> 7], 1);
                ++nl;
            }
        }
        __syncthreads();
        for (int i = tid; i < NB; i += 256) {
            int h = hist[i];
            base[i] = h ? atomicAdd(&gcnt[i], h) : 0;
        }
        __syncthreads();
        for (int i = tid; i < NB; i += 256) hist[i] = 0;  // reuse as cursor
        __syncthreads();
        for (int k = 0; k < nl; ++k) {
            int bb = dv[k] >> 7;
            int r = base[bb] + atomicAdd(&hist[bb], 1);
            if (r < BCAP)
                ebuf[(size_t)bb * BCAP + r] = ((long long)sv[k] << 32) | (unsigned)dv[k];
        }
    } else {
        // zero the 128 B dummy row (index N_NODES) of all 3 fp8 mirrors
        if (tid < 32) ((unsigned*)(qx + FEAT_ELEMS))[tid] = 0;
        else if (tid < 64) ((unsigned*)(q1 + FEAT_ELEMS))[tid - 32] = 0;
        else if (tid < 96) ((unsigned*)(q0 + FEAT_ELEMS))[tid - 64] = 0;
    }
}

// ---------------- Phase B: per-bucket padded-CSR build (LDS atomics only) -------
// List padding to x8 folded into the per-node epilogue (dummy idx N_NODES ->
// zero fp8 row), eliminating all gather tail iterations.

__global__ __launch_bounds__(256) void build_kernel(const int* __restrict__ gcnt,
                                                    const long long* __restrict__ ebuf,
                                                    int* __restrict__ cnt,
                                                    int* __restrict__ col_idx) {
    __shared__ int cur[128];
    const int b = blockIdx.x;
    const int tid = threadIdx.x;
    if (tid < 128) cur[tid] = 0;
    __syncthreads();
    int n = gcnt[b];
    if (n > BCAP) n = BCAP;
    const long long* eb = ebuf + (size_t)b * BCAP;
    for (int i = tid; i < n; i += 256) {
        long long p = eb[i];
        int d = (int)(p & 0xFFFFFFFFll);
        int s = (int)(p >> 32);
        int slot = atomicAdd(&cur[d & 127], 1);
        if (slot < STRIDE) col_idx[d * STRIDE + slot] = s;
    }
    __syncthreads();
    int node = b * 128 + tid;
    if (tid < 128 && node < N_NODES) {
        int c = cur[tid];
        if (c > STRIDE) c = STRIDE;
        const int p = (c + 7) & ~7;  // pad to multiple of 8
        for (int s = c; s < p; ++s) col_idx[node * STRIDE + s] = N_NODES;
        cnt[node] = p;
    }
}

// ---------------- Fused GIN layer: 2-wave block per 16-row tile ----------------
// Block = 128 thr (2 waves) per 16-row tile -> 6250 waves (6.1/SIMD).
// Gather: batches-only loop (lists padded to x8, dummy -> zero row);
//   indices via 2x int4 (direct .xyzw, no address-taking); neighbor loads
//   8 x uint2 named scalars -- the proven no-spill width (uint4 spilled, r8/r10;
//   split-mirror 2-pass regressed, r14). t -> shared tl (row&7 swizzle).
// MFMA passes split by column halves: wave w computes ct = w*4..w*4+3.
//   pass1 reads full t rows (B1); u -> ul (B2); pass2; h' -> tl (B3).
// LDS: tl 4 KB + ul 4 KB = 8 KB/block. 3 __syncthreads on 2-wave blocks.
// LAST=false: epi-2b coalesced read-back + residual -> fp16 state + fp8 mirror.
// LAST=true: pass 3 = h3 @ Wh + bh -> fp32 out (head fused).

template <bool LAST>
__global__ __launch_bounds__(128, 4) void gin_layer_kernel(
    const __half* __restrict__ Hs,        // fp16 state (self + residual source)
    const unsigned char* __restrict__ Qm, // fp8 message mirror (+ zero row)
    const int* __restrict__ cnt,
    const int* __restrict__ col_idx,
    const __half* __restrict__ W1f,
    const __half* __restrict__ W2f,
    const __half* __restrict__ Whf,       // head W frags (LAST only)
    const float* __restrict__ b1,
    const float* __restrict__ b2,
    const float* __restrict__ bh,         // head bias (LAST only)
    __half* __restrict__ Hout,
    unsigned char* __restrict__ Qout,
    float* __restrict__ Cout) {
    __shared__ __align__(16) __half tl[2048];  // 16x128 t tile; reused for h'
    __shared__ __align__(16) __half ul[2048];  // 16x128 u tile
    const int tid = threadIdx.x;
    const int lane = tid & 63;
    const int wid = tid >> 6;   // 0..1: column-half owner
    const int c = lane & 15;
    const int q = lane >> 4;
    const int R = blockIdx.x * 16;  // tile rows (50000 = 3125*16, grid exact)

    // ---- Phase G: gather t = h[v] + sum_fp8 h[src] -> tl (fp16, swizzled) ----
    {
        const int g = tid >> 4;          // row-in-group 0..7
        const int d0 = (tid & 15) * 8;   // 8-half chunk
#define ACCQ(U)                                                             \
    {                                                                       \
        f32x2 g0 = __builtin_amdgcn_cvt_pk_f32_fp8((int)(U).x, false);      \
        f32x2 g1 = __builtin_amdgcn_cvt_pk_f32_fp8((int)(U).x, true);       \
        f32x2 g2 = __builtin_amdgcn_cvt_pk_f32_fp8((int)(U).y, false);      \
        f32x2 g3 = __builtin_amdgcn_cvt_pk_f32_fp8((int)(U).y, true);       \
        acc[0] += g0.x; acc[1] += g0.y; acc[2] += g1.x; acc[3] += g1.y;     \
        acc[4] += g2.x; acc[5] += g2.y; acc[6] += g3.x; acc[7] += g3.y;     \
    }
#pragma unroll
        for (int it = 0; it < 2; ++it) {
            const int rl = it * 8 + g;   // local row 0..15
            const size_t grow = (size_t)(R + rl);
            float acc[8];
            {
                uint4 sv = *(const uint4*)(Hs + grow * DIM + d0);
                const __half2* sp = (const __half2*)&sv;
                float2 s0 = __half22float2(sp[0]), s1 = __half22float2(sp[1]);
                float2 s2 = __half22float2(sp[2]), s3 = __half22float2(sp[3]);
                acc[0] = s0.x; acc[1] = s0.y; acc[2] = s1.x; acc[3] = s1.y;
                acc[4] = s2.x; acc[5] = s2.y; acc[6] = s3.x; acc[7] = s3.y;
            }
            const int d = cnt[grow];  // padded multiple of 8, <= 64
            const int* ci = col_idx + grow * STRIDE;
            for (int j = 0; j < d; j += 8) {
                int4 ia = *(const int4*)(ci + j);
                int4 ib = *(const int4*)(ci + j + 4);
                uint2 u0 = *(const uint2*)(Qm + (size_t)ia.x * DIM + d0);
                uint2 u1 = *(const uint2*)(Qm + (size_t)ia.y * DIM + d0);
                uint2 u2 = *(const uint2*)(Qm + (size_t)ia.z * DIM + d0);
                uint2 u3 = *(const uint2*)(Qm + (size_t)ia.w * DIM + d0);
                uint2 u4 = *(const uint2*)(Qm + (size_t)ib.x * DIM + d0);
                uint2 u5 = *(const uint2*)(Qm + (size_t)ib.y * DIM + d0);
                uint2 u6 = *(const uint2*)(Qm + (size_t)ib.z * DIM + d0);
                uint2 u7 = *(const uint2*)(Qm + (size_t)ib.w * DIM + d0);
                ACCQ(u0) ACCQ(u1) ACCQ(u2) ACCQ(u3)
                ACCQ(u4) ACCQ(u5) ACCQ(u6) ACCQ(u7)
            }
            uint4 o;
            __half2* op = (__half2*)&o;
            op[0] = __floats2half2_rn(acc[0], acc[1]);
            op[1] = __floats2half2_rn(acc[2], acc[3]);
            op[2] = __floats2half2_rn(acc[4], acc[5]);
            op[3] = __floats2half2_rn(acc[6], acc[7]);
            *(uint4*)&tl[rl * 128 + (d0 ^ ((rl & 7) << 3))] = o;
        }
#undef ACCQ
    }
    __syncthreads();  // B1: t tile complete

    // ---- A frags from tl (rows 0..15 = both waves' gather output) ----
    f16x8 a[4];
#pragma unroll
    for (int ks = 0; ks < 4; ++ks)
        a[ks] = *(const f16x8*)&tl[c * 128 + ((ks * 32 + q * 8) ^ ((c & 7) << 3))];

    // ---- pass 1: u(16x64 per wave) = t @ W1 (B frags streamed from L2) ----
    f32x4 acc1[4];
#pragma unroll
    for (int t = 0; t < 4; ++t) acc1[t] = (f32x4){0.f, 0.f, 0.f, 0.f};
#pragma unroll
    for (int ks = 0; ks < 4; ++ks) {
#pragma unroll
        for (int t = 0; t < 4; ++t) {
            const int ctg = wid * 4 + t;
            f16x8 b = *(const f16x8*)(W1f + (ks * 8 + ctg) * 512 + lane * 8);
            acc1[t] = MFMA_F16(a[ks], b, acc1[t], 0, 0, 0);
        }
    }

    // ---- epilogue 1: relu(u + b1) -> ul (row&7 swizzle) ----
#pragma unroll
    for (int t = 0; t < 4; ++t) {
        const int col = (wid * 4 + t) * 16 + c;
        const float bv = b1[col];
#pragma unroll
        for (int rr = 0; rr < 4; ++rr) {
            const int rl = q * 4 + rr;
            ul[rl * 128 + (col ^ ((rl & 7) << 3))] =
                __float2half(fmaxf(acc1[t][rr] + bv, 0.f));
        }
    }
    __syncthreads();  // B2: u tile complete (also: all t reads done)

    // ---- pass 2: h' = u @ W2 (full u rows; own column half) ----
    f32x4 acc2[4];
#pragma unroll
    for (int t = 0; t < 4; ++t) acc2[t] = (f32x4){0.f, 0.f, 0.f, 0.f};
#pragma unroll
    for (int ks = 0; ks < 4; ++ks) {
        f16x8 ua = *(const f16x8*)&ul[c * 128 + ((ks * 32 + q * 8) ^ ((c & 7) << 3))];
#pragma unroll
        for (int t = 0; t < 4; ++t) {
            const int ctg = wid * 4 + t;
            f16x8 b = *(const f16x8*)(W2f + (ks * 8 + ctg) * 512 + lane * 8);
            acc2[t] = MFMA_F16(ua, b, acc2[t], 0, 0, 0);
        }
    }

    // ---- epilogue 2a: +b2 -> tl (t dead; q<<4 swizzle: addr = f(row,col)) ----
#pragma unroll
    for (int t = 0; t < 4; ++t) {
        const int col = (wid * 4 + t) * 16 + c;
        const float bv = b2[col];
#pragma unroll
        for (int rr = 0; rr < 4; ++rr) {
            const int rl = q * 4 + rr;
            tl[rl * 128 + (col ^ (q << 4))] = __float2half(acc2[t][rr] + bv);
        }
    }
    __syncthreads();  // B3: h' tile complete

    if (!LAST) {
        // ---- epi 2b: coalesced read-back + residual -> fp16 state + fp8 ----
        // 128 thr: 8 thr/row, 16 halfs each (chunks c0 and c0+64)
        const int row2 = tid >> 3;       // 0..15
        const int cb = (tid & 7) * 8;
        const size_t grow = (size_t)(R + row2);
#pragma unroll
        for (int k = 0; k < 2; ++k) {
            const int c0 = cb + k * 64;
            uint4 hv = *(uint4*)&tl[row2 * 128 + (c0 ^ ((row2 >> 2) << 4))];
            const __half2* hp = (const __half2*)&hv;
            float2 t0 = __half22float2(hp[0]), t1 = __half22float2(hp[1]);
            float2 t2 = __half22float2(hp[2]), t3 = __half22float2(hp[3]);
            float f0 = t0.x, f1 = t0.y, f2 = t1.x, f3 = t1.y;
            float f4 = t2.x, f5 = t2.y, f6 = t3.x, f7 = t3.y;
            {
                uint4 rv = *(const uint4*)(Hs + grow * DIM + c0);
                const __half2* rp = (const __half2*)&rv;
                float2 r0 = __half22float2(rp[0]), r1 = __half22float2(rp[1]);
                float2 r2 = __half22float2(rp[2]), r3 = __half22float2(rp[3]);
                f0 += r0.x; f1 += r0.y; f2 += r1.x; f3 += r1.y;
                f4 += r2.x; f5 += r2.y; f6 += r3.x; f7 += r3.y;
            }
            uint4 ov;
            __half2* op = (__half2*)&ov;
            op[0] = __floats2half2_rn(f0, f1);
            op[1] = __floats2half2_rn(f2, f3);
            op[2] = __floats2half2_rn(f4, f5);
            op[3] = __floats2half2_rn(f6, f7);
            *(uint4*)(Hout + grow * DIM + c0) = ov;
            int q0 = __builtin_amdgcn_cvt_pk_fp8_f32(f0, f1, 0, false);
            q0 = __builtin_amdgcn_cvt_pk_fp8_f32(f2, f3, q0, true);
            int q1 = __builtin_amdgcn_cvt_pk_fp8_f32(f4, f5, 0, false);
            q1 = __builtin_amdgcn_cvt_pk_fp8_f32(f6, f7, q1, true);
            uint2 qv;
            qv.x = (unsigned)q0;
            qv.y = (unsigned)q1;
            *(uint2*)(Qout + grow * DIM + c0) = qv;
        }
    } else {
        // ---- pass 3 (head): out = h3 @ Wh + bh -> fp32 (own column half) ----
        f32x4 acc3[4];
#pragma unroll
        for (int t = 0; t < 4; ++t) acc3[t] = (f32x4){0.f, 0.f, 0.f, 0.f};
#pragma unroll
        for (int ks = 0; ks < 4; ++ks) {
            f16x8 ha =
                *(const f16x8*)&tl[c * 128 + ((ks * 32 + q * 8) ^ ((c >> 2) << 4))];
#pragma unroll
            for (int t = 0; t < 4; ++t) {
                const int ctg = wid * 4 + t;
                f16x8 b = *(const f16x8*)(Whf + (ks * 8 + ctg) * 512 + lane * 8);
                acc3[t] = MFMA_F16(ha, b, acc3[t], 0, 0, 0);
            }
        }
#pragma unroll
        for (int t = 0; t < 4; ++t) {
            const int col = (wid * 4 + t) * 16 + c;
            const float bv = bh[col];
#pragma unroll
            for (int rr = 0; rr < 4; ++rr) {
                const int row = R + q * 4 + rr;
                Cout[(size_t)row * DIM + col] = acc3[t][rr] + bv;
            }
        }
    }
}

// ---------------- Launch ----------------

extern "C" void kernel_launch(void* const* d_in, const int* in_sizes, int n_in,
                              void* d_out, int out_size, void* d_ws, size_t ws_size,
                              hipStream_t stream) {
    const float* x = (const float*)d_in[0];
    const int* ei = (const int*)d_in[1];
    const float* w1[3] = {(const float*)d_in[2], (const float*)d_in[6], (const float*)d_in[10]};
    const float* b1[3] = {(const float*)d_in[3], (const float*)d_in[7], (const float*)d_in[11]};
    const float* w2[3] = {(const float*)d_in[4], (const float*)d_in[8], (const float*)d_in[12]};
    const float* b2[3] = {(const float*)d_in[5], (const float*)d_in[9], (const float*)d_in[13]};
    const float* wh = (const float*)d_in[14];
    const float* bh = (const float*)d_in[15];
    float* out = (float*)d_out;

    char* ws = (char*)d_ws;
    const size_t HFEAT = (size_t)FEAT_ELEMS * sizeof(__half);  // 12.8 MB
    const size_t QFEAT = (size_t)FEAT_ELEMS + 256;             // 6.4 MB + pad row
    size_t off = 0;
    int* cnt = (int*)(ws + off);                         off += 200704;
    int* col_idx = (int*)(ws + off);                     off += (size_t)N_NODES * STRIDE * 4;
    int* gcnt = (int*)(ws + off);                        off += 4096;
    __half* Wf = (__half*)(ws + off);                    off += 7 * 32768;
    long long* ebuf = (long long*)(ws + off);            off += (size_t)NB * BCAP * 8;
    __half* HMx = (__half*)(ws + off);                   off += HFEAT;  // x fp16
    __half* HM1 = (__half*)(ws + off);                   off += HFEAT;  // h1 fp16
    __half* HM0 = (__half*)(ws + off);                   off += HFEAT;  // h2 fp16
    unsigned char* Qx = (unsigned char*)(ws + off);      off += QFEAT;  // x fp8
    unsigned char* Q1 = (unsigned char*)(ws + off);      off += QFEAT;  // h1 fp8
    unsigned char* Q0 = (unsigned char*)(ws + off);      off += QFEAT;  // h2 fp8

    const int GIN_BLKS = N_NODES / 16;  // 3125 (2 waves per 16-row tile)

    // ---- prep+bucket (merged) + padded-CSR build ----
    (void)hipMemsetAsync(gcnt, 0, NB * sizeof(int), stream);
    prep_bucket_kernel<<<1528, 256, 0, stream>>>(
        w1[0], w2[0], w1[1], w2[1], w1[2], w2[2], wh, Wf, x, HMx,
        Qx, Q1, Q0, ei, gcnt, ebuf);
    build_kernel<<<NB, 256, 0, stream>>>(gcnt, ebuf, cnt, col_idx);

#define WF(i) (Wf + (size_t)(i) * 16384)

    // Layer 0: gather(HMx, Qx) + MLP (res=HMx) -> HM1 + Q1
    gin_layer_kernel<false><<<GIN_BLKS, 128, 0, stream>>>(
        HMx, Qx, cnt, col_idx, WF(0), WF(1), nullptr, b1[0], b2[0], nullptr,
        HM1, Q1, nullptr);

    // Layer 1: gather(HM1, Q1) + MLP (res=HM1) -> HM0 + Q0
    gin_layer_kernel<false><<<GIN_BLKS, 128, 0, stream>>>(
        HM1, Q1, cnt, col_idx, WF(2), WF(3), nullptr, b1[1], b2[1], nullptr,
        HM0, Q0, nullptr);

    // Layer 2 + head: gather(HM0, Q0) + MLP (no res) + h3@wh+bh -> out fp32
    gin_layer_kernel<true><<<GIN_BLKS, 128, 0, stream>>>(
        HM0, Q0, cnt, col_idx, WF(4), WF(5), WF(6), b1[2], b2[2], bh,
        nullptr, nullptr, out);
#undef WF
}